// Round 9
// baseline (289.643 us; speedup 1.0000x reference)
//
#include <hip/hip_runtime.h>
#include <hip/hip_bf16.h>
#include <cstdint>
#include <cstddef>

#define N_TOK   8192
#define D_MODEL 1024
#define D_FFN   4096
#define K_TOP   512
#define NHALF   2048   // FFN half-width processed per round

typedef __bf16 bf16_t;
typedef __bf16 bf16x8 __attribute__((ext_vector_type(8)));
typedef __bf16 bf16x4 __attribute__((ext_vector_type(4)));
typedef float  f32x4  __attribute__((ext_vector_type(4)));

// ---------------- aux kernels ----------------

__global__ void cvt_f32_bf16(const float* __restrict__ in, bf16_t* __restrict__ out, int n4) {
  int i = blockIdx.x * blockDim.x + threadIdx.x;
  if (i < n4) {
    const f32x4 v = ((const f32x4*)in)[i];
    bf16x4 o;
    o[0] = (bf16_t)v[0]; o[1] = (bf16_t)v[1]; o[2] = (bf16_t)v[2]; o[3] = (bf16_t)v[3];
    ((bf16x4*)out)[i] = o;
  }
}

// in: [rows][cols] f32  ->  out: [cols][rows] bf16   (B^T layout for GEMM)
__global__ void transpose_cvt(const float* __restrict__ in, bf16_t* __restrict__ out,
                              int rows, int cols) {
  __shared__ float tile[32][33];
  const int tx = threadIdx.x, ty = threadIdx.y;
  const int x = blockIdx.x * 32 + tx;
#pragma unroll
  for (int i = 0; i < 32; i += 8) {
    int y = blockIdx.y * 32 + ty + i;
    tile[ty + i][tx] = in[(size_t)y * cols + x];
  }
  __syncthreads();
  const int xo = blockIdx.y * 32 + tx;
#pragma unroll
  for (int i = 0; i < 32; i += 8) {
    int yo = blockIdx.x * 32 + ty + i;
    out[(size_t)yo * rows + xo] = (bf16_t)tile[tx][ty + i];
  }
}

// multiplicity counts, packed 8 x 4-bit nibbles per u32, per-row LDS histogram
#define ROWS_PER_BLK 4
__global__ __launch_bounds__(256) void count_scatter_lds(
    const int* __restrict__ idx, unsigned int* __restrict__ M) {
  __shared__ unsigned int loc[ROWS_PER_BLK * (D_FFN / 8)];   // 8 KB
  const int t = threadIdx.x;
  const int r0 = blockIdx.x * ROWS_PER_BLK;

#pragma unroll
  for (int i = 0; i < ROWS_PER_BLK * (D_FFN / 8) / 256; ++i)
    loc[t + i * 256] = 0;
  __syncthreads();

  const int* ip = idx + (size_t)r0 * K_TOP;
#pragma unroll
  for (int i = 0; i < ROWS_PER_BLK * K_TOP / 256; ++i) {
    const int e = t + i * 256;
    const int lr = e >> 9;
    const int j = ip[e];
    atomicAdd(&loc[lr * (D_FFN / 8) + (j >> 3)], 1u << ((j & 7) * 4));
  }
  __syncthreads();

  unsigned int* op = M + (size_t)r0 * (D_FFN / 8);
#pragma unroll
  for (int i = 0; i < ROWS_PER_BLK * (D_FFN / 8) / 256; ++i)
    op[t + i * 256] = loc[t + i * 256];
}

// ---------------- GEMM common ----------------

__device__ __forceinline__ void gload_lds16(const void* g, void* l) {
#if __has_builtin(__builtin_amdgcn_global_load_lds)
  __builtin_amdgcn_global_load_lds((__attribute__((address_space(1))) void*)(g),
                                   (__attribute__((address_space(3))) void*)(l), 16, 0, 0);
#else
  *(bf16x8*)l = *(const bf16x8*)g;
#endif
}

// 16 MFMA: ACC[m][n] += AF[m] * BF[n]
#define MFMA16(ACC, AF, BF)                                                      \
  _Pragma("unroll")                                                              \
  for (int m = 0; m < 4; ++m)                                                    \
    _Pragma("unroll")                                                            \
    for (int n = 0; n < 4; ++n)                                                  \
      ACC[m][n] = __builtin_amdgcn_mfma_f32_16x16x32_bf16(AF[m], BF[n], ACC[m][n], 0, 0, 0);

// ---------------- GEMM1: gate+up fused, 2-phase 256x128 (big clusters) -----
// Per-phase fixed cost measured ~890 cyc (R6-R8) vs 620 cyc matrix for 16-MFMA
// phases -> merge to 32-MFMA clusters: P1 = G x (k0,k1), P2 = U x (k0,k1),
// af fragments shared. Barriers 9 -> 3 per K-tile. sched_barrier dropped
// (m141: order-pinning hurts; compiler lgkm tracking is near-optimal).
#define BM1 256
#define BN1 128
#define BK1 64
#define NT1 (D_MODEL / BK1)   // 16 K-tiles
#define LDSBUF 65536          // bytes per double-buffer half

__global__ __launch_bounds__(512, 2) void gemm_gateup_2p(
    const bf16_t* __restrict__ A,    // [N_TOK][D_MODEL]
    const bf16_t* __restrict__ Bg,   // [D_FFN][D_MODEL]
    const bf16_t* __restrict__ Bu,   // [D_FFN][D_MODEL]
    const unsigned int* __restrict__ cnt,
    bf16_t* __restrict__ Z,          // [N_TOK][NHALF]
    int n_base)
{
  extern __shared__ char smem[];
  const int t = threadIdx.x;
  const int lane = t & 63;
  const int w = t >> 6;            // 0..7
  const int wr = w >> 1;           // 0..3 (M)
  const int wc = w & 1;            // 0..1 (N)
  const int l15 = lane & 15;
  const int grp = lane >> 4;       // 0..3

  // T1 XCD swizzle (nwg = 512, %8==0 -> simple bijective form)
  const int nwg = gridDim.x * gridDim.y;
  int flat = blockIdx.x + gridDim.x * blockIdx.y;
  flat = (flat & 7) * (nwg >> 3) + (flat >> 3);
  const int m0 = (flat % gridDim.x) * BM1;
  const int n0 = (flat / gridDim.x) * BN1;

  // ---- stage: per-lane global element-offsets (inverse-swizzled) ----
  int offA[4], offB[2];
#pragma unroll
  for (int c = 0; c < 4; ++c) {
    const int s = c * 512 + w * 64 + lane;          // A slot 0..2047
    const int r = s >> 3, cb = (s & 7) ^ (r & 7);
    offA[c] = (m0 + r) * D_MODEL + cb * 8;
  }
#pragma unroll
  for (int c = 0; c < 2; ++c) {
    const int s = c * 512 + w * 64 + lane;          // B slot 0..1023
    const int r = s >> 3, cb = (s & 7) ^ (r & 7);
    offB[c] = (n_base + n0 + r) * D_MODEL + cb * 8;
  }
  const int dst0 = (w * 64 + lane) * 16;            // linear LDS dest (bytes)

  // ---- ds_read byte offsets (swizzled; verified R6: conflicts -> 0) ----
  const int swz = l15 & 7;
  const int a_k0 = wr * 8192 + l15 * 128 + ((0 + grp) ^ swz) * 16;
  const int a_k1 = wr * 8192 + l15 * 128 + ((4 + grp) ^ swz) * 16;
  const int bg_k0 = 32768 + wc * 8192 + l15 * 128 + ((0 + grp) ^ swz) * 16;
  const int bg_k1 = 32768 + wc * 8192 + l15 * 128 + ((4 + grp) ^ swz) * 16;
  const int bu_k0 = bg_k0 + 16384;
  const int bu_k1 = bg_k1 + 16384;

  // ---- prologue: stage K-tile 0 into buffer 0 ----
#pragma unroll
  for (int c = 0; c < 4; ++c) gload_lds16(A + offA[c], smem + dst0 + c * 8192);
#pragma unroll
  for (int c = 0; c < 2; ++c) gload_lds16(Bg + offB[c], smem + 32768 + dst0 + c * 8192);
#pragma unroll
  for (int c = 0; c < 2; ++c) gload_lds16(Bu + offB[c], smem + 49152 + dst0 + c * 8192);
  asm volatile("s_waitcnt vmcnt(0)" ::: "memory");
  __builtin_amdgcn_s_barrier();

  f32x4 accg[4][4] = {};
  f32x4 accu[4][4] = {};

  for (int tt = 0; tt < NT1; ++tt) {
    char* rb = smem + (tt & 1) * LDSBUF;
    char* wb = smem + ((tt & 1) ^ 1) * LDSBUF;
    const int kg = (tt + 1) * BK1;
    const bool st = (tt + 1 < NT1);
    bf16x8 af0[4], af1[4], bg0[4], bg1[4], bu0[4], bu1[4];

    // ---- P1: G x (k0,k1), 32 MFMA ----
#pragma unroll
    for (int m = 0; m < 4; ++m) {
      af0[m] = *(const bf16x8*)(rb + a_k0 + m * 2048);
      af1[m] = *(const bf16x8*)(rb + a_k1 + m * 2048);
    }
#pragma unroll
    for (int n = 0; n < 4; ++n) {
      bg0[n] = *(const bf16x8*)(rb + bg_k0 + n * 2048);
      bg1[n] = *(const bf16x8*)(rb + bg_k1 + n * 2048);
    }
    if (st) {   // all next-tile staging issued here; drained end-of-iter
#pragma unroll
      for (int c = 0; c < 4; ++c) gload_lds16(A + offA[c] + kg, wb + dst0 + c * 8192);
#pragma unroll
      for (int c = 0; c < 2; ++c) gload_lds16(Bg + offB[c] + kg, wb + 32768 + dst0 + c * 8192);
#pragma unroll
      for (int c = 0; c < 2; ++c) gload_lds16(Bu + offB[c] + kg, wb + 49152 + dst0 + c * 8192);
    }
    __builtin_amdgcn_s_barrier();
    asm volatile("s_waitcnt lgkmcnt(0)" ::: "memory");
    __builtin_amdgcn_s_setprio(1);
    MFMA16(accg, af0, bg0);
    MFMA16(accg, af1, bg1);
    __builtin_amdgcn_s_setprio(0);
    __builtin_amdgcn_s_barrier();

    // ---- P2: U x (k0,k1), 32 MFMA (af reused from P1) ----
#pragma unroll
    for (int n = 0; n < 4; ++n) {
      bu0[n] = *(const bf16x8*)(rb + bu_k0 + n * 2048);
      bu1[n] = *(const bf16x8*)(rb + bu_k1 + n * 2048);
    }
    asm volatile("s_waitcnt lgkmcnt(0)" ::: "memory");
    __builtin_amdgcn_s_setprio(1);
    MFMA16(accu, af0, bu0);
    MFMA16(accu, af1, bu1);
    __builtin_amdgcn_s_setprio(0);
    if (st) asm volatile("s_waitcnt vmcnt(0)" ::: "memory");
    __builtin_amdgcn_s_barrier();
  }

  // ---- epilogue: Z = cnt * u * silu(g) ----
#pragma unroll
  for (int m = 0; m < 4; ++m) {
#pragma unroll
    for (int n = 0; n < 4; ++n) {
      const int colL = n0 + wc * 64 + n * 16 + l15;
      const int jg = n_base + colL;
#pragma unroll
      for (int j = 0; j < 4; ++j) {
        const int row = m0 + wr * 64 + m * 16 + grp * 4 + j;
        float g = accg[m][n][j];
        float u = accu[m][n][j];
        unsigned int cw = cnt[(size_t)row * (D_FFN / 8) + (jg >> 3)];
        float c = (float)((cw >> ((jg & 7) * 4)) & 15u);
        float z = c * u * (g / (1.0f + __expf(-g)));
        Z[(size_t)row * NHALF + colL] = (bf16_t)z;
      }
    }
  }
}

// ---------------- GEMM2: down, 1-phase 256x128 (32-MFMA cluster) -----------
#define BM2 256
#define BN2 128
#define BK2 64
#define NT2 (NHALF / BK2)     // 32 K-tiles
#define LDSBUF2 49152

__global__ __launch_bounds__(512, 2) void gemm_down_1p(
    const bf16_t* __restrict__ A,    // Z [N_TOK][NHALF]
    const bf16_t* __restrict__ B,    // [D_MODEL][D_FFN]  (w_down^T)
    float* __restrict__ C,           // [N_TOK][D_MODEL]
    int k_base, int accum)
{
  extern __shared__ char smem[];
  const int t = threadIdx.x;
  const int lane = t & 63;
  const int w = t >> 6;
  const int wr = w >> 1;           // 0..3 (M)
  const int wc = w & 1;            // 0..1 (N)
  const int l15 = lane & 15;
  const int grp = lane >> 4;

  const int nwg = gridDim.x * gridDim.y;  // 256, %8==0
  int flat = blockIdx.x + gridDim.x * blockIdx.y;
  flat = (flat & 7) * (nwg >> 3) + (flat >> 3);
  const int m0 = (flat % gridDim.x) * BM2;
  const int n0 = (flat / gridDim.x) * BN2;

  int offA[4], offB[2];
#pragma unroll
  for (int c = 0; c < 4; ++c) {
    const int s = c * 512 + w * 64 + lane;
    const int r = s >> 3, cb = (s & 7) ^ (r & 7);
    offA[c] = (m0 + r) * NHALF + cb * 8;
  }
#pragma unroll
  for (int c = 0; c < 2; ++c) {
    const int s = c * 512 + w * 64 + lane;
    const int r = s >> 3, cb = (s & 7) ^ (r & 7);
    offB[c] = (n0 + r) * D_FFN + k_base + cb * 8;
  }
  const int dst0 = (w * 64 + lane) * 16;

  const int swz = l15 & 7;
  const int a_k0 = wr * 8192 + l15 * 128 + ((0 + grp) ^ swz) * 16;
  const int a_k1 = wr * 8192 + l15 * 128 + ((4 + grp) ^ swz) * 16;
  const int b_k0 = 32768 + wc * 8192 + l15 * 128 + ((0 + grp) ^ swz) * 16;
  const int b_k1 = 32768 + wc * 8192 + l15 * 128 + ((4 + grp) ^ swz) * 16;

  // prologue: tile 0 -> buf 0
#pragma unroll
  for (int c = 0; c < 4; ++c) gload_lds16(A + offA[c], smem + dst0 + c * 8192);
#pragma unroll
  for (int c = 0; c < 2; ++c) gload_lds16(B + offB[c], smem + 32768 + dst0 + c * 8192);
  asm volatile("s_waitcnt vmcnt(0)" ::: "memory");
  __builtin_amdgcn_s_barrier();

  f32x4 acc[4][4] = {};

  for (int tt = 0; tt < NT2; ++tt) {
    char* rb = smem + (tt & 1) * LDSBUF2;
    char* wb = smem + ((tt & 1) ^ 1) * LDSBUF2;
    const int kg = (tt + 1) * BK2;
    const bool st = (tt + 1 < NT2);
    bf16x8 af0[4], af1[4], bf0[4], bf1[4];

    // single phase: 16 ds_read + 6 stage + 32 MFMA
#pragma unroll
    for (int m = 0; m < 4; ++m) {
      af0[m] = *(const bf16x8*)(rb + a_k0 + m * 2048);
      af1[m] = *(const bf16x8*)(rb + a_k1 + m * 2048);
    }
#pragma unroll
    for (int n = 0; n < 4; ++n) {
      bf0[n] = *(const bf16x8*)(rb + b_k0 + n * 2048);
      bf1[n] = *(const bf16x8*)(rb + b_k1 + n * 2048);
    }
    if (st) {
#pragma unroll
      for (int c = 0; c < 4; ++c) gload_lds16(A + offA[c] + kg, wb + dst0 + c * 8192);
#pragma unroll
      for (int c = 0; c < 2; ++c) gload_lds16(B + offB[c] + kg, wb + 32768 + dst0 + c * 8192);
    }
    __builtin_amdgcn_s_barrier();
    asm volatile("s_waitcnt lgkmcnt(0)" ::: "memory");
    __builtin_amdgcn_s_setprio(1);
    MFMA16(acc, af0, bf0);
    MFMA16(acc, af1, bf1);
    __builtin_amdgcn_s_setprio(0);
    if (st) asm volatile("s_waitcnt vmcnt(0)" ::: "memory");
    __builtin_amdgcn_s_barrier();
  }

  // epilogue
#pragma unroll
  for (int m = 0; m < 4; ++m) {
#pragma unroll
    for (int n = 0; n < 4; ++n) {
      const int col = n0 + wc * 64 + n * 16 + l15;
#pragma unroll
      for (int j = 0; j < 4; ++j) {
        const int row = m0 + wr * 64 + m * 16 + grp * 4 + j;
        const size_t off = (size_t)row * D_MODEL + col;
        float prev = accum ? C[off] : 0.0f;
        C[off] = prev + acc[m][n][j];
      }
    }
  }
}

// ---------------- launch ----------------

extern "C" void kernel_launch(void* const* d_in, const int* in_sizes, int n_in,
                              void* d_out, int out_size, void* d_ws, size_t ws_size,
                              hipStream_t stream) {
  const float* x  = (const float*)d_in[0];
  const int*   idx = (const int*)d_in[1];
  const float* wg = (const float*)d_in[2];
  const float* wu = (const float*)d_in[3];
  const float* wd = (const float*)d_in[4];
  float* out = (float*)d_out;

  char* ws = (char*)d_ws;
  const size_t SZ_XB  = (size_t)N_TOK * D_MODEL * 2;   // 16 MB
  const size_t SZ_W   = (size_t)D_MODEL * D_FFN * 2;   //  8 MB each
  const size_t SZ_CNT = (size_t)N_TOK * D_FFN / 2;     // 16 MB
  bf16_t* xb  = (bf16_t*)(ws);
  bf16_t* wgT = (bf16_t*)(ws + SZ_XB);
  bf16_t* wuT = (bf16_t*)(ws + SZ_XB + SZ_W);
  bf16_t* wdT = (bf16_t*)(ws + SZ_XB + 2 * SZ_W);
  unsigned int* cnt = (unsigned int*)(ws + SZ_XB + 3 * SZ_W);
  bf16_t* Z   = (bf16_t*)(ws + SZ_XB + 3 * SZ_W + SZ_CNT);  // [N_TOK][NHALF]
  // total ws use: 16 + 24 + 16 + 32 = 88 MB

  (void)hipFuncSetAttribute((const void*)gemm_gateup_2p,
                            hipFuncAttributeMaxDynamicSharedMemorySize, 131072);
  (void)hipFuncSetAttribute((const void*)gemm_down_1p,
                            hipFuncAttributeMaxDynamicSharedMemorySize, 98304);

  count_scatter_lds<<<N_TOK / ROWS_PER_BLK, 256, 0, stream>>>(idx, cnt);
  cvt_f32_bf16<<<(N_TOK * D_MODEL / 4 + 255) / 256, 256, 0, stream>>>(x, xb, N_TOK * D_MODEL / 4);
  transpose_cvt<<<dim3(D_FFN / 32, D_MODEL / 32), dim3(32, 8), 0, stream>>>(wg, wgT, D_MODEL, D_FFN);
  transpose_cvt<<<dim3(D_FFN / 32, D_MODEL / 32), dim3(32, 8), 0, stream>>>(wu, wuT, D_MODEL, D_FFN);
  transpose_cvt<<<dim3(D_MODEL / 32, D_FFN / 32), dim3(32, 8), 0, stream>>>(wd, wdT, D_FFN, D_MODEL);

  // two FFN halves, Z buffer reused (stream-ordered)
  gemm_gateup_2p<<<dim3(N_TOK / BM1, NHALF / BN1), 512, 131072, stream>>>(xb, wgT, wuT, cnt, Z, 0);
  gemm_down_1p<<<dim3(N_TOK / BM2, D_MODEL / BN2), 512, 98304, stream>>>(Z, wdT, out, 0, 0);
  gemm_gateup_2p<<<dim3(N_TOK / BM1, NHALF / BN1), 512, 131072, stream>>>(xb, wgT, wuT, cnt, Z, NHALF);
  gemm_down_1p<<<dim3(N_TOK / BM2, D_MODEL / BN2), 512, 98304, stream>>>(Z, wdT, out, NHALF, 1);
}

// Round 10
// 266.528 us; speedup vs baseline: 1.0867x; 1.0867x over previous
//
#include <hip/hip_runtime.h>
#include <hip/hip_bf16.h>
#include <cstdint>
#include <cstddef>

#define N_TOK   8192
#define D_MODEL 1024
#define D_FFN   4096
#define K_TOP   512
#define NHALF   2048   // FFN half-width processed per round

typedef __bf16 bf16_t;
typedef __bf16 bf16x8 __attribute__((ext_vector_type(8)));
typedef __bf16 bf16x4 __attribute__((ext_vector_type(4)));
typedef float  f32x4  __attribute__((ext_vector_type(4)));

// ---------------- aux kernels ----------------

__global__ void cvt_f32_bf16(const float* __restrict__ in, bf16_t* __restrict__ out, int n4) {
  int i = blockIdx.x * blockDim.x + threadIdx.x;
  if (i < n4) {
    const f32x4 v = ((const f32x4*)in)[i];
    bf16x4 o;
    o[0] = (bf16_t)v[0]; o[1] = (bf16_t)v[1]; o[2] = (bf16_t)v[2]; o[3] = (bf16_t)v[3];
    ((bf16x4*)out)[i] = o;
  }
}

// in: [rows][cols] f32  ->  out: [cols][rows] bf16   (B^T layout for GEMM)
__global__ void transpose_cvt(const float* __restrict__ in, bf16_t* __restrict__ out,
                              int rows, int cols) {
  __shared__ float tile[32][33];
  const int tx = threadIdx.x, ty = threadIdx.y;
  const int x = blockIdx.x * 32 + tx;
#pragma unroll
  for (int i = 0; i < 32; i += 8) {
    int y = blockIdx.y * 32 + ty + i;
    tile[ty + i][tx] = in[(size_t)y * cols + x];
  }
  __syncthreads();
  const int xo = blockIdx.y * 32 + tx;
#pragma unroll
  for (int i = 0; i < 32; i += 8) {
    int yo = blockIdx.x * 32 + ty + i;
    out[(size_t)yo * rows + xo] = (bf16_t)tile[tx][ty + i];
  }
}

// multiplicity counts, packed 8 x 4-bit nibbles per u32, per-row LDS histogram
#define ROWS_PER_BLK 4
__global__ __launch_bounds__(256) void count_scatter_lds(
    const int* __restrict__ idx, unsigned int* __restrict__ M) {
  __shared__ unsigned int loc[ROWS_PER_BLK * (D_FFN / 8)];   // 8 KB
  const int t = threadIdx.x;
  const int r0 = blockIdx.x * ROWS_PER_BLK;

#pragma unroll
  for (int i = 0; i < ROWS_PER_BLK * (D_FFN / 8) / 256; ++i)
    loc[t + i * 256] = 0;
  __syncthreads();

  const int* ip = idx + (size_t)r0 * K_TOP;
#pragma unroll
  for (int i = 0; i < ROWS_PER_BLK * K_TOP / 256; ++i) {
    const int e = t + i * 256;
    const int lr = e >> 9;
    const int j = ip[e];
    atomicAdd(&loc[lr * (D_FFN / 8) + (j >> 3)], 1u << ((j & 7) * 4));
  }
  __syncthreads();

  unsigned int* op = M + (size_t)r0 * (D_FFN / 8);
#pragma unroll
  for (int i = 0; i < ROWS_PER_BLK * (D_FFN / 8) / 256; ++i)
    op[t + i * 256] = loc[t + i * 256];
}

// ---------------- GEMM common ----------------

__device__ __forceinline__ void gload_lds16(const void* g, void* l) {
#if __has_builtin(__builtin_amdgcn_global_load_lds)
  __builtin_amdgcn_global_load_lds((__attribute__((address_space(1))) void*)(g),
                                   (__attribute__((address_space(3))) void*)(l), 16, 0, 0);
#else
  *(bf16x8*)l = *(const bf16x8*)g;
#endif
}

// 16 MFMA: ACC[m][n] += AF[m] * BF[n]
#define MFMA16(ACC, AF, BF)                                                      \
  _Pragma("unroll")                                                              \
  for (int m = 0; m < 4; ++m)                                                    \
    _Pragma("unroll")                                                            \
    for (int n = 0; n < 4; ++n)                                                  \
      ACC[m][n] = __builtin_amdgcn_mfma_f32_16x16x32_bf16(AF[m], BF[n], ACC[m][n], 0, 0, 0);

// ---------------- GEMM1: gate+up fused, 2-phase 256x128 (big clusters) -----
// Fixed cost ~800-880 cyc/phase (R6-R8 model) -> 32-MFMA clusters:
// P1 = G x (k0,k1), P2 = U x (k0,k1), af shared. Barriers 9 -> 3 per K-tile.
// NO XCD swizzle: R9's swizzle put 32 same-B blocks on one XCD (16MB A set,
// L2 thrash, FETCH 53->143MB). Default dispatch order is already L2-friendly
// (4 same-B blocks + 4 A-panels = 2MB per XCD).
#define BM1 256
#define BN1 128
#define BK1 64
#define NT1 (D_MODEL / BK1)   // 16 K-tiles
#define LDSBUF 65536          // bytes per double-buffer half

__global__ __launch_bounds__(512, 2) void gemm_gateup_2p(
    const bf16_t* __restrict__ A,    // [N_TOK][D_MODEL]
    const bf16_t* __restrict__ Bg,   // [D_FFN][D_MODEL]
    const bf16_t* __restrict__ Bu,   // [D_FFN][D_MODEL]
    const unsigned int* __restrict__ cnt,
    bf16_t* __restrict__ Z,          // [N_TOK][NHALF]
    int n_base)
{
  extern __shared__ char smem[];
  const int t = threadIdx.x;
  const int lane = t & 63;
  const int w = t >> 6;            // 0..7
  const int wr = w >> 1;           // 0..3 (M)
  const int wc = w & 1;            // 0..1 (N)
  const int l15 = lane & 15;
  const int grp = lane >> 4;       // 0..3
  const int m0 = blockIdx.x * BM1;
  const int n0 = blockIdx.y * BN1;

  // ---- stage: per-lane global element-offsets (inverse-swizzled) ----
  int offA[4], offB[2];
#pragma unroll
  for (int c = 0; c < 4; ++c) {
    const int s = c * 512 + w * 64 + lane;          // A slot 0..2047
    const int r = s >> 3, cb = (s & 7) ^ (r & 7);
    offA[c] = (m0 + r) * D_MODEL + cb * 8;
  }
#pragma unroll
  for (int c = 0; c < 2; ++c) {
    const int s = c * 512 + w * 64 + lane;          // B slot 0..1023
    const int r = s >> 3, cb = (s & 7) ^ (r & 7);
    offB[c] = (n_base + n0 + r) * D_MODEL + cb * 8;
  }
  const int dst0 = (w * 64 + lane) * 16;            // linear LDS dest (bytes)

  // ---- ds_read byte offsets (swizzled; verified R6: conflicts -> 0) ----
  const int swz = l15 & 7;
  const int a_k0 = wr * 8192 + l15 * 128 + ((0 + grp) ^ swz) * 16;
  const int a_k1 = wr * 8192 + l15 * 128 + ((4 + grp) ^ swz) * 16;
  const int bg_k0 = 32768 + wc * 8192 + l15 * 128 + ((0 + grp) ^ swz) * 16;
  const int bg_k1 = 32768 + wc * 8192 + l15 * 128 + ((4 + grp) ^ swz) * 16;
  const int bu_k0 = bg_k0 + 16384;
  const int bu_k1 = bg_k1 + 16384;

  // ---- prologue: stage K-tile 0 into buffer 0 ----
#pragma unroll
  for (int c = 0; c < 4; ++c) gload_lds16(A + offA[c], smem + dst0 + c * 8192);
#pragma unroll
  for (int c = 0; c < 2; ++c) gload_lds16(Bg + offB[c], smem + 32768 + dst0 + c * 8192);
#pragma unroll
  for (int c = 0; c < 2; ++c) gload_lds16(Bu + offB[c], smem + 49152 + dst0 + c * 8192);
  asm volatile("s_waitcnt vmcnt(0)" ::: "memory");
  __builtin_amdgcn_s_barrier();

  f32x4 accg[4][4] = {};
  f32x4 accu[4][4] = {};

  for (int tt = 0; tt < NT1; ++tt) {
    char* rb = smem + (tt & 1) * LDSBUF;
    char* wb = smem + ((tt & 1) ^ 1) * LDSBUF;
    const int kg = (tt + 1) * BK1;
    const bool st = (tt + 1 < NT1);
    bf16x8 af0[4], af1[4], bg0[4], bg1[4], bu0[4], bu1[4];

    // ---- P1: G x (k0,k1), 32 MFMA ----
#pragma unroll
    for (int m = 0; m < 4; ++m) {
      af0[m] = *(const bf16x8*)(rb + a_k0 + m * 2048);
      af1[m] = *(const bf16x8*)(rb + a_k1 + m * 2048);
    }
#pragma unroll
    for (int n = 0; n < 4; ++n) {
      bg0[n] = *(const bf16x8*)(rb + bg_k0 + n * 2048);
      bg1[n] = *(const bf16x8*)(rb + bg_k1 + n * 2048);
    }
    if (st) {   // all next-tile staging issued here; drained end-of-iter
#pragma unroll
      for (int c = 0; c < 4; ++c) gload_lds16(A + offA[c] + kg, wb + dst0 + c * 8192);
#pragma unroll
      for (int c = 0; c < 2; ++c) gload_lds16(Bg + offB[c] + kg, wb + 32768 + dst0 + c * 8192);
#pragma unroll
      for (int c = 0; c < 2; ++c) gload_lds16(Bu + offB[c] + kg, wb + 49152 + dst0 + c * 8192);
    }
    __builtin_amdgcn_s_barrier();
    asm volatile("s_waitcnt lgkmcnt(0)" ::: "memory");
    __builtin_amdgcn_s_setprio(1);
    MFMA16(accg, af0, bg0);
    MFMA16(accg, af1, bg1);
    __builtin_amdgcn_s_setprio(0);
    __builtin_amdgcn_s_barrier();

    // ---- P2: U x (k0,k1), 32 MFMA (af reused from P1) ----
#pragma unroll
    for (int n = 0; n < 4; ++n) {
      bu0[n] = *(const bf16x8*)(rb + bu_k0 + n * 2048);
      bu1[n] = *(const bf16x8*)(rb + bu_k1 + n * 2048);
    }
    asm volatile("s_waitcnt lgkmcnt(0)" ::: "memory");
    __builtin_amdgcn_s_setprio(1);
    MFMA16(accu, af0, bu0);
    MFMA16(accu, af1, bu1);
    __builtin_amdgcn_s_setprio(0);
    if (st) asm volatile("s_waitcnt vmcnt(0)" ::: "memory");
    __builtin_amdgcn_s_barrier();
  }

  // ---- epilogue: Z = cnt * u * silu(g) ----
#pragma unroll
  for (int m = 0; m < 4; ++m) {
#pragma unroll
    for (int n = 0; n < 4; ++n) {
      const int colL = n0 + wc * 64 + n * 16 + l15;
      const int jg = n_base + colL;
#pragma unroll
      for (int j = 0; j < 4; ++j) {
        const int row = m0 + wr * 64 + m * 16 + grp * 4 + j;
        float g = accg[m][n][j];
        float u = accu[m][n][j];
        unsigned int cw = cnt[(size_t)row * (D_FFN / 8) + (jg >> 3)];
        float c = (float)((cw >> ((jg & 7) * 4)) & 15u);
        float z = c * u * (g / (1.0f + __expf(-g)));
        Z[(size_t)row * NHALF + colL] = (bf16_t)z;
      }
    }
  }
}

// ---------------- GEMM2: down, 1-phase 256x128 (32-MFMA cluster) -----------
#define BM2 256
#define BN2 128
#define BK2 64
#define NT2 (NHALF / BK2)     // 32 K-tiles
#define LDSBUF2 49152

__global__ __launch_bounds__(512, 2) void gemm_down_1p(
    const bf16_t* __restrict__ A,    // Z [N_TOK][NHALF]
    const bf16_t* __restrict__ B,    // [D_MODEL][D_FFN]  (w_down^T)
    float* __restrict__ C,           // [N_TOK][D_MODEL]
    int k_base, int accum)
{
  extern __shared__ char smem[];
  const int t = threadIdx.x;
  const int lane = t & 63;
  const int w = t >> 6;
  const int wr = w >> 1;           // 0..3 (M)
  const int wc = w & 1;            // 0..1 (N)
  const int l15 = lane & 15;
  const int grp = lane >> 4;
  const int m0 = blockIdx.x * BM2;
  const int n0 = blockIdx.y * BN2;

  int offA[4], offB[2];
#pragma unroll
  for (int c = 0; c < 4; ++c) {
    const int s = c * 512 + w * 64 + lane;
    const int r = s >> 3, cb = (s & 7) ^ (r & 7);
    offA[c] = (m0 + r) * NHALF + cb * 8;
  }
#pragma unroll
  for (int c = 0; c < 2; ++c) {
    const int s = c * 512 + w * 64 + lane;
    const int r = s >> 3, cb = (s & 7) ^ (r & 7);
    offB[c] = (n0 + r) * D_FFN + k_base + cb * 8;
  }
  const int dst0 = (w * 64 + lane) * 16;

  const int swz = l15 & 7;
  const int a_k0 = wr * 8192 + l15 * 128 + ((0 + grp) ^ swz) * 16;
  const int a_k1 = wr * 8192 + l15 * 128 + ((4 + grp) ^ swz) * 16;
  const int b_k0 = 32768 + wc * 8192 + l15 * 128 + ((0 + grp) ^ swz) * 16;
  const int b_k1 = 32768 + wc * 8192 + l15 * 128 + ((4 + grp) ^ swz) * 16;

  // prologue: tile 0 -> buf 0
#pragma unroll
  for (int c = 0; c < 4; ++c) gload_lds16(A + offA[c], smem + dst0 + c * 8192);
#pragma unroll
  for (int c = 0; c < 2; ++c) gload_lds16(B + offB[c], smem + 32768 + dst0 + c * 8192);
  asm volatile("s_waitcnt vmcnt(0)" ::: "memory");
  __builtin_amdgcn_s_barrier();

  f32x4 acc[4][4] = {};

  for (int tt = 0; tt < NT2; ++tt) {
    char* rb = smem + (tt & 1) * LDSBUF2;
    char* wb = smem + ((tt & 1) ^ 1) * LDSBUF2;
    const int kg = (tt + 1) * BK2;
    const bool st = (tt + 1 < NT2);
    bf16x8 af0[4], af1[4], bf0[4], bf1[4];

    // single phase: 16 ds_read + 6 stage + 32 MFMA
#pragma unroll
    for (int m = 0; m < 4; ++m) {
      af0[m] = *(const bf16x8*)(rb + a_k0 + m * 2048);
      af1[m] = *(const bf16x8*)(rb + a_k1 + m * 2048);
    }
#pragma unroll
    for (int n = 0; n < 4; ++n) {
      bf0[n] = *(const bf16x8*)(rb + b_k0 + n * 2048);
      bf1[n] = *(const bf16x8*)(rb + b_k1 + n * 2048);
    }
    if (st) {
#pragma unroll
      for (int c = 0; c < 4; ++c) gload_lds16(A + offA[c] + kg, wb + dst0 + c * 8192);
#pragma unroll
      for (int c = 0; c < 2; ++c) gload_lds16(B + offB[c] + kg, wb + 32768 + dst0 + c * 8192);
    }
    __builtin_amdgcn_s_barrier();
    asm volatile("s_waitcnt lgkmcnt(0)" ::: "memory");
    __builtin_amdgcn_s_setprio(1);
    MFMA16(acc, af0, bf0);
    MFMA16(acc, af1, bf1);
    __builtin_amdgcn_s_setprio(0);
    if (st) asm volatile("s_waitcnt vmcnt(0)" ::: "memory");
    __builtin_amdgcn_s_barrier();
  }

  // epilogue
#pragma unroll
  for (int m = 0; m < 4; ++m) {
#pragma unroll
    for (int n = 0; n < 4; ++n) {
      const int col = n0 + wc * 64 + n * 16 + l15;
#pragma unroll
      for (int j = 0; j < 4; ++j) {
        const int row = m0 + wr * 64 + m * 16 + grp * 4 + j;
        const size_t off = (size_t)row * D_MODEL + col;
        float prev = accum ? C[off] : 0.0f;
        C[off] = prev + acc[m][n][j];
      }
    }
  }
}

// ---------------- launch ----------------

extern "C" void kernel_launch(void* const* d_in, const int* in_sizes, int n_in,
                              void* d_out, int out_size, void* d_ws, size_t ws_size,
                              hipStream_t stream) {
  const float* x  = (const float*)d_in[0];
  const int*   idx = (const int*)d_in[1];
  const float* wg = (const float*)d_in[2];
  const float* wu = (const float*)d_in[3];
  const float* wd = (const float*)d_in[4];
  float* out = (float*)d_out;

  char* ws = (char*)d_ws;
  const size_t SZ_XB  = (size_t)N_TOK * D_MODEL * 2;   // 16 MB
  const size_t SZ_W   = (size_t)D_MODEL * D_FFN * 2;   //  8 MB each
  const size_t SZ_CNT = (size_t)N_TOK * D_FFN / 2;     // 16 MB
  bf16_t* xb  = (bf16_t*)(ws);
  bf16_t* wgT = (bf16_t*)(ws + SZ_XB);
  bf16_t* wuT = (bf16_t*)(ws + SZ_XB + SZ_W);
  bf16_t* wdT = (bf16_t*)(ws + SZ_XB + 2 * SZ_W);
  unsigned int* cnt = (unsigned int*)(ws + SZ_XB + 3 * SZ_W);
  bf16_t* Z   = (bf16_t*)(ws + SZ_XB + 3 * SZ_W + SZ_CNT);  // [N_TOK][NHALF]
  // total ws use: 16 + 24 + 16 + 32 = 88 MB

  (void)hipFuncSetAttribute((const void*)gemm_gateup_2p,
                            hipFuncAttributeMaxDynamicSharedMemorySize, 131072);
  (void)hipFuncSetAttribute((const void*)gemm_down_1p,
                            hipFuncAttributeMaxDynamicSharedMemorySize, 98304);

  count_scatter_lds<<<N_TOK / ROWS_PER_BLK, 256, 0, stream>>>(idx, cnt);
  cvt_f32_bf16<<<(N_TOK * D_MODEL / 4 + 255) / 256, 256, 0, stream>>>(x, xb, N_TOK * D_MODEL / 4);
  transpose_cvt<<<dim3(D_FFN / 32, D_MODEL / 32), dim3(32, 8), 0, stream>>>(wg, wgT, D_MODEL, D_FFN);
  transpose_cvt<<<dim3(D_FFN / 32, D_MODEL / 32), dim3(32, 8), 0, stream>>>(wu, wuT, D_MODEL, D_FFN);
  transpose_cvt<<<dim3(D_MODEL / 32, D_FFN / 32), dim3(32, 8), 0, stream>>>(wd, wdT, D_FFN, D_MODEL);

  // two FFN halves, Z buffer reused (stream-ordered)
  gemm_gateup_2p<<<dim3(N_TOK / BM1, NHALF / BN1), 512, 131072, stream>>>(xb, wgT, wuT, cnt, Z, 0);
  gemm_down_1p<<<dim3(N_TOK / BM2, D_MODEL / BN2), 512, 98304, stream>>>(Z, wdT, out, 0, 0);
  gemm_gateup_2p<<<dim3(N_TOK / BM1, NHALF / BN1), 512, 131072, stream>>>(xb, wgT, wuT, cnt, Z, NHALF);
  gemm_down_1p<<<dim3(N_TOK / BM2, D_MODEL / BN2), 512, 98304, stream>>>(Z, wdT, out, NHALF, 1);
}